// Round 13
// baseline (143.523 us; speedup 1.0000x reference)
//
#include <hip/hip_runtime.h>
#include <hip/hip_bf16.h>

#define NB 32
#define IN_DIM 256
#define NT 512
#define NL 512
#define NCONN 256
#define LN_EPS 1e-3f
#define M_TOT (NB * NT)   // 16384 rows

typedef __attribute__((ext_vector_type(8))) short short8;
typedef __attribute__((ext_vector_type(4))) float f32x4;

__device__ __forceinline__ void async_copy16(void* lds_dst, const void* g_src) {
    __builtin_amdgcn_global_load_lds(
        (const __attribute__((address_space(1))) unsigned int*)g_src,
        (__attribute__((address_space(3))) unsigned int*)lds_dst, 16, 0, 0);
}

__device__ __forceinline__ ushort f2bf(float f) {   // RNE f32->bf16 bits
    unsigned int x = __float_as_uint(f);
    return (ushort)((x + 0x7FFFu + ((x >> 16) & 1u)) >> 16);
}

// ---------------------------------------------------------------------------
// wprep: all weight transposes + ihb fill in ONE launch.
// blocks 0-63: Wi->Btig(k0), 64-127: Ri->Btig(k512), 128-191: Wg->Btig2(k0),
// 192-255: Rg->Btig2(k512), 256-287: Wf->WfT, 288-319: Wc->Btc, 320: ihb.
// ---------------------------------------------------------------------------
__global__ __launch_bounds__(256) void wprep(
    const float* __restrict__ Wi, const float* __restrict__ Ri,
    const float* __restrict__ Wg, const float* __restrict__ Rg,
    const float* __restrict__ Wf, const float* __restrict__ Wc,
    const float* __restrict__ init_h,
    __hip_bfloat16* __restrict__ Btig, __hip_bfloat16* __restrict__ WfT,
    __hip_bfloat16* __restrict__ Btc, __hip_bfloat16* __restrict__ ihb)
{
    const int blk = blockIdx.x;
    const int tid = threadIdx.x;
    if (blk == 320) {
        ihb[tid]       = __float2bfloat16(init_h[tid]);
        ihb[tid + 256] = __float2bfloat16(init_h[tid + 256]);
        return;
    }
    const float* src; __hip_bfloat16* dst;
    int N, lddst, k_off, tile;
    if (blk < 64)       { src = Wi; dst = Btig; N = 512; lddst = 1024; k_off = 0;   tile = blk; }
    else if (blk < 128) { src = Ri; dst = Btig; N = 512; lddst = 1024; k_off = 512; tile = blk - 64; }
    else if (blk < 192) { src = Wg; dst = Btig + (size_t)512 * 1024; N = 512; lddst = 1024; k_off = 0;   tile = blk - 128; }
    else if (blk < 256) { src = Rg; dst = Btig + (size_t)512 * 1024; N = 512; lddst = 1024; k_off = 512; tile = blk - 192; }
    else if (blk < 288) { src = Wf; dst = WfT; N = 512; lddst = 256; k_off = 0; tile = blk - 256; }
    else                { src = Wc; dst = Btc; N = 512; lddst = 256; k_off = 0; tile = blk - 288; }

    __shared__ float t[64][65];
    const int ntn = N >> 6;
    const int k0 = (tile / ntn) << 6;
    const int n0 = (tile % ntn) << 6;
    for (int idx = tid; idx < 4096; idx += 256) {
        const int kk = idx >> 6, nn = idx & 63;
        t[kk][nn] = src[(size_t)(k0 + kk) * N + n0 + nn];
    }
    __syncthreads();
    for (int idx = tid; idx < 4096; idx += 256) {
        const int nn = idx >> 6, kk = idx & 63;
        dst[(size_t)(n0 + nn) * lddst + k_off + k0 + kk] = __float2bfloat16(t[kk][nn]);
    }
}

// ---------------------------------------------------------------------------
// Kernel 1 (MFMA 16x16x32): P = x^T @ Wf (64 t-rows x 512 cols per block),
// A staged IN-KERNEL from f32 x[b][k][t], p = cos(P+bf), LN, zbuf bf16.
// ---------------------------------------------------------------------------
__global__ __launch_bounds__(512, 2) void k1_mfma_fourier_ln(
    const float* __restrict__ x,              // [NB][256][512] f32
    const __hip_bfloat16* __restrict__ WfT,   // [512][256]
    const float* __restrict__ bf, const float* __restrict__ gamma,
    const float* __restrict__ beta,
    __hip_bfloat16* __restrict__ zb)
{
    constexpr int ABYTES = 64 * 128;          // 8 KB
    constexpr int BBYTES = 512 * 128;         // 64 KB
    constexpr int NBUFB  = ABYTES + BBYTES;
    __shared__ __align__(16) char lds[2 * NBUFB];     // 144 KB
    __shared__ float pS[64][8], pQ[64][8];
    __shared__ float mS[64], rS[64];

    const int tid  = threadIdx.x;
    const int wave = tid >> 6, lane = tid & 63;
    const int m0 = blockIdx.x * 64;
    const int b  = m0 >> 9;
    const int t0 = m0 & 511;
    const float* xb = x + (size_t)b * IN_DIM * NT;

    f32x4 acc[4][4];
#pragma unroll
    for (int mi = 0; mi < 4; mi++)
#pragma unroll
        for (int ni = 0; ni < 4; ni++) acc[mi][ni] = f32x4{0.f, 0.f, 0.f, 0.f};

    const int rowq = tid >> 3;
    const int sswz = ((tid & 7) ^ (rowq & 7)) << 4;
    const char* Bb = (const char*)WfT;

    auto stage = [&](int buf, int kt) {
        char* base = lds + buf * NBUFB;
#pragma unroll
        for (int j = 0; j < 2; j++) {
            const int ci = j * 512 + tid;
            const int k  = ci >> 4;
            const int tc = ci & 15;
            const float4 v = *(const float4*)(
                xb + ((size_t)(kt * 64 + k)) * NT + t0 + tc * 4);
            const ushort h[4] = {f2bf(v.x), f2bf(v.y), f2bf(v.z), f2bf(v.w)};
            const int sl = k >> 3, kb2 = (k & 7) << 1;
#pragma unroll
            for (int e = 0; e < 4; e++) {
                const int t = tc * 4 + e;
                *(ushort*)(base + t * 128 + (((sl) ^ (t & 7)) << 4) + kb2) = h[e];
            }
        }
        const size_t kb = (size_t)kt * 128;
#pragma unroll
        for (int j = 0; j < 8; j++) {
            const int row = j * 64 + rowq;
            async_copy16(base + ABYTES + (j * 512 + tid) * 16,
                         Bb + (size_t)row * 512 + kb + sswz);
        }
    };

    const int l15 = lane & 15, lq = lane >> 4, l7 = lane & 7;
    int kxB[2];
#pragma unroll
    for (int ks = 0; ks < 2; ks++) kxB[ks] = ((ks * 4 + lq) ^ l7) << 4;

    stage(0, 0);
    int cur = 0;
#pragma unroll 1
    for (int kt = 0; kt < 4; kt++) {
        __syncthreads();
        if (kt + 1 < 4) stage(cur ^ 1, kt + 1);
        const char* sA = lds + cur * NBUFB;
        const char* sB = sA + ABYTES;
#pragma unroll
        for (int ks = 0; ks < 2; ks++) {
            const int kx = kxB[ks];
            short8 a[4], b[4];
#pragma unroll
            for (int mi = 0; mi < 4; mi++)
                a[mi] = *(const short8*)(sA + (size_t)(mi * 16 + l15) * 128 + kx);
#pragma unroll
            for (int ni = 0; ni < 4; ni++)
                b[ni] = *(const short8*)(sB +
                    (size_t)(wave * 64 + ni * 16 + l15) * 128 + kx);
#pragma unroll
            for (int ni = 0; ni < 4; ni++)
#pragma unroll
                for (int mi = 0; mi < 4; mi++)
                    acc[mi][ni] = __builtin_amdgcn_mfma_f32_16x16x32_bf16(
                        a[mi], b[ni], acc[mi][ni], 0, 0, 0);
        }
        cur ^= 1;
    }

    int cg[4]; float bfc[4];
#pragma unroll
    for (int ni = 0; ni < 4; ni++) {
        cg[ni] = wave * 64 + ni * 16 + l15;
        bfc[ni] = bf[cg[ni]];
    }

#pragma unroll
    for (int mi = 0; mi < 4; mi++) {
#pragma unroll
        for (int r = 0; r < 4; r++) {
            float s = 0.f, q = 0.f;
#pragma unroll
            for (int ni = 0; ni < 4; ni++) {
                const float p = __cosf(acc[mi][ni][r] + bfc[ni]);
                s += p; q += p * p;
            }
#pragma unroll
            for (int off = 8; off >= 1; off >>= 1) {
                s += __shfl_xor(s, off);
                q += __shfl_xor(q, off);
            }
            if (l15 == 0) {
                const int row = mi * 16 + lq * 4 + r;
                pS[row][wave] = s;
                pQ[row][wave] = q;
            }
        }
    }
    __syncthreads();
    if (tid < 64) {
        float a = 0.f, qq = 0.f;
#pragma unroll
        for (int w = 0; w < 8; w++) { a += pS[tid][w]; qq += pQ[tid][w]; }
        const float mu = a * (1.0f / NL);
        const float var = qq * (1.0f / NL) - mu * mu;
        mS[tid] = mu;
        rS[tid] = rsqrtf(var + LN_EPS);
    }
    __syncthreads();

    float gm[4], bt[4];
#pragma unroll
    for (int ni = 0; ni < 4; ni++) { gm[ni] = gamma[cg[ni]]; bt[ni] = beta[cg[ni]]; }

#pragma unroll
    for (int mi = 0; mi < 4; mi++) {
#pragma unroll
        for (int r = 0; r < 4; r++) {
            const int row = mi * 16 + lq * 4 + r;
            const int m = m0 + row;
            const float mu = mS[row], rs = rS[row];
#pragma unroll
            for (int ni = 0; ni < 4; ni++) {
                const float p = __cosf(acc[mi][ni][r] + bfc[ni]);
                const float z = gm[ni] * (p - mu) * rs + bt[ni];
                zb[(size_t)m * 512 + cg[ni]] = __float2bfloat16(z);
            }
        }
    }
}

// ---------------------------------------------------------------------------
// Gates fused: 1024 blocks; type=(d>>3)&1 (0=iu, 1=f); idx pairs iu/f of the
// SAME tile onto the SAME XCD (d and d+8). 128x128 tile, 4 waves, single
// 32 KB buffer (2-phase).  iu: u-phase (conn@Wc, reg-staged) + main GEMM;
// f: main GEMM only. A stitched: K<512 zbuf[m], K>=512 zbuf[m-1]/ihb.
// ---------------------------------------------------------------------------
#define STAGE_AZ(kt)                                                          \
    {                                                                         \
        _Pragma("unroll")                                                     \
        for (int j = 0; j < 4; j++) {                                         \
            const int i = j * 256 + tid;                                      \
            const int r = i >> 3;                                             \
            const int sl = (i & 7) ^ (r & 7);                                 \
            const int ke = (kt) * 64 + sl * 8;                                \
            const __hip_bfloat16* srcA;                                       \
            const int m = m0 + r;                                             \
            if (ke < 512) {                                                   \
                srcA = Az + (size_t)m * 512 + ke;                             \
            } else {                                                          \
                const int k2 = ke - 512;                                      \
                srcA = ((m & (NT - 1)) == 0) ? (ihb + k2)                     \
                                             : (Az + (size_t)(m - 1) * 512 + k2); \
            }                                                                 \
            async_copy16(lds + i * 16, srcA);                                 \
            async_copy16(lds + 16384 + i * 16,                                \
                         Bg + (size_t)(n0 + r) * 1024 + ke);                  \
        }                                                                     \
    }

#define COMPUTE_TILE(ACC)                                                     \
    {                                                                         \
        const char* sA = lds;                                                 \
        const char* sB = lds + 16384;                                         \
        _Pragma("unroll")                                                     \
        for (int ks = 0; ks < 2; ks++) {                                      \
            short8 a[4], b[4];                                                \
            _Pragma("unroll")                                                 \
            for (int mi = 0; mi < 4; mi++)                                    \
                a[mi] = *(const short8*)(sA +                                 \
                    (size_t)(wm * 64 + mi * 16 + l15) * 128 + kx[ks]);        \
            _Pragma("unroll")                                                 \
            for (int ni = 0; ni < 4; ni++)                                    \
                b[ni] = *(const short8*)(sB +                                 \
                    (size_t)(wn * 64 + ni * 16 + l15) * 128 + kx[ks]);        \
            _Pragma("unroll")                                                 \
            for (int ni = 0; ni < 4; ni++)                                    \
                _Pragma("unroll")                                             \
                for (int mi = 0; mi < 4; mi++)                                \
                    ACC[mi][ni] = __builtin_amdgcn_mfma_f32_16x16x32_bf16(    \
                        a[mi], b[ni], ACC[mi][ni], 0, 0, 0);                  \
        }                                                                     \
    }

__global__ __launch_bounds__(256, 3) void gates_fused(
    const __hip_bfloat16* __restrict__ Az,
    const __hip_bfloat16* __restrict__ Btig,
    const float* __restrict__ conn,
    const __hip_bfloat16* __restrict__ Btc,
    const __hip_bfloat16* __restrict__ ihb,
    const float* __restrict__ bi, const float* __restrict__ bg,
    const float* __restrict__ bc,
    __hip_bfloat16* __restrict__ fb, __hip_bfloat16* __restrict__ ub)
{
    __shared__ __align__(16) char lds[32768];
    const int tid  = threadIdx.x;
    const int wave = tid >> 6, lane = tid & 63;
    const int wm = wave >> 1, wn = wave & 1;
    const int d = blockIdx.x;
    const int type = (d >> 3) & 1;                  // 0 = iu, 1 = f
    const int idx  = ((d >> 4) << 3) | (d & 7);     // 0..511, pair-on-XCD
    const int L = (idx & 7) * 64 + (idx >> 3);      // XCD-contiguous tiles
    const int m0 = (L >> 2) << 7;
    const int n0 = (L & 3) << 7;
    const int l15 = lane & 15, lq = lane >> 4, l7 = lane & 7;
    int kx[2];
    kx[0] = (lq ^ l7) << 4;
    kx[1] = ((4 + lq) ^ l7) << 4;

    const __hip_bfloat16* Bg = Btig + (type ? (size_t)512 * 1024 : 0);

    if (type == 0) {
        // ---- u phase: conn (f32 reg-staged) @ Wc^T, K=256 ----
        f32x4 accu[4][4];
#pragma unroll
        for (int mi = 0; mi < 4; mi++)
#pragma unroll
            for (int ni = 0; ni < 4; ni++) accu[mi][ni] = f32x4{0.f, 0.f, 0.f, 0.f};

#pragma unroll 1
        for (int kt = 0; kt < 4; kt++) {
#pragma unroll
            for (int j = 0; j < 8; j++) {
                const int ci = j * 256 + tid;
                const int r  = ci >> 4;
                const int c4 = ci & 15;
                const float4 v = *(const float4*)(
                    conn + (size_t)(m0 + r) * NCONN + kt * 64 + c4 * 4);
                ushort4 h;
                h.x = f2bf(v.x); h.y = f2bf(v.y); h.z = f2bf(v.z); h.w = f2bf(v.w);
                const int sl = c4 >> 1, half = c4 & 1;
                *(ushort4*)(lds + r * 128 + ((sl ^ (r & 7)) << 4) + half * 8) = h;
            }
#pragma unroll
            for (int j = 0; j < 4; j++) {
                const int i = j * 256 + tid;
                const int r = i >> 3;
                const int sl = (i & 7) ^ (r & 7);
                const int ke = kt * 64 + sl * 8;
                async_copy16(lds + 16384 + i * 16,
                             Btc + (size_t)(n0 + r) * NCONN + ke);
            }
            __syncthreads();
            COMPUTE_TILE(accu)
            __syncthreads();
        }

        // ---- main: [z|z_prev] @ [Wi;Ri]^T, K=1024 ----
        f32x4 acc[4][4];
#pragma unroll
        for (int mi = 0; mi < 4; mi++)
#pragma unroll
            for (int ni = 0; ni < 4; ni++) acc[mi][ni] = f32x4{0.f, 0.f, 0.f, 0.f};

#pragma unroll 1
        for (int kt = 0; kt < 16; kt++) {
            STAGE_AZ(kt)
            __syncthreads();
            COMPUTE_TILE(acc)
            __syncthreads();
        }

#pragma unroll
        for (int ni = 0; ni < 4; ni++) {
            const int gcol = n0 + wn * 64 + ni * 16 + l15;
            const float bil = bi[gcol], bcl = bc[gcol];
#pragma unroll
            for (int mi = 0; mi < 4; mi++)
#pragma unroll
                for (int r = 0; r < 4; r++) {
                    const int m = m0 + wm * 64 + mi * 16 + lq * 4 + r;
                    const float iv = 1.f / (1.f + __expf(-(acc[mi][ni][r] + bil)));
                    const float uv = accu[mi][ni][r] + bcl;
                    ub[(size_t)m * 512 + gcol] = __float2bfloat16(iv * uv);
                }
        }
    } else {
        // ---- f: [z|z_prev] @ [Wg;Rg]^T, K=1024 ----
        f32x4 acc[4][4];
#pragma unroll
        for (int mi = 0; mi < 4; mi++)
#pragma unroll
            for (int ni = 0; ni < 4; ni++) acc[mi][ni] = f32x4{0.f, 0.f, 0.f, 0.f};

#pragma unroll 1
        for (int kt = 0; kt < 16; kt++) {
            STAGE_AZ(kt)
            __syncthreads();
            COMPUTE_TILE(acc)
            __syncthreads();
        }

#pragma unroll
        for (int ni = 0; ni < 4; ni++) {
            const int gcol = n0 + wn * 64 + ni * 16 + l15;
            const float bgl = bg[gcol];
#pragma unroll
            for (int mi = 0; mi < 4; mi++)
#pragma unroll
                for (int r = 0; r < 4; r++) {
                    const int m = m0 + wm * 64 + mi * 16 + lq * 4 + r;
                    const float fv = 1.f / (1.f + __expf(-(acc[mi][ni][r] + bgl)));
                    fb[(size_t)m * 512 + gcol] = __float2bfloat16(fv);
                }
        }
    }
}

// ---------------------------------------------------------------------------
// Kernel 3: sequential scan; h = sin(z)*c; out[b,l,t].
// ---------------------------------------------------------------------------
__global__ __launch_bounds__(64) void k3_scan(
    const __hip_bfloat16* __restrict__ zb,
    const __hip_bfloat16* __restrict__ fb,
    const __hip_bfloat16* __restrict__ ub,
    const float* __restrict__ init_c, float* __restrict__ out)
{
    const int b = blockIdx.x >> 3;
    const int l = ((blockIdx.x & 7) << 6) + threadIdx.x;
    float c = init_c[l];

    const __hip_bfloat16* zp = zb + (size_t)b * NT * 512 + l;
    const __hip_bfloat16* fp = fb + (size_t)b * NT * NL + l;
    const __hip_bfloat16* ip = ub + (size_t)b * NT * NL + l;
    float* op = out + ((size_t)b * NL + l) * NT;

    for (int t0 = 0; t0 < NT; t0 += 16) {
        float fv[16], iv[16], zv[16];
#pragma unroll
        for (int j = 0; j < 16; j++) {
            fv[j] = __bfloat162float(fp[(size_t)(t0 + j) * NL]);
            iv[j] = __bfloat162float(ip[(size_t)(t0 + j) * NL]);
            zv[j] = __bfloat162float(zp[(size_t)(t0 + j) * 512]);
        }
        float h[16];
#pragma unroll
        for (int j = 0; j < 16; j++) {
            c = fv[j] * c + iv[j];
            h[j] = __sinf(zv[j]) * c;
        }
        float4* o4 = (float4*)(op + t0);
        o4[0] = make_float4(h[0],  h[1],  h[2],  h[3]);
        o4[1] = make_float4(h[4],  h[5],  h[6],  h[7]);
        o4[2] = make_float4(h[8],  h[9],  h[10], h[11]);
        o4[3] = make_float4(h[12], h[13], h[14], h[15]);
    }
}

// ---------------------------------------------------------------------------
extern "C" void kernel_launch(void* const* d_in, const int* in_sizes, int n_in,
                              void* d_out, int out_size, void* d_ws, size_t ws_size,
                              hipStream_t stream)
{
    const float* x      = (const float*)d_in[0];
    const float* conn   = (const float*)d_in[1];
    const float* Wf     = (const float*)d_in[2];
    const float* bfv    = (const float*)d_in[3];
    const float* gamma  = (const float*)d_in[4];
    const float* beta   = (const float*)d_in[5];
    const float* Wi     = (const float*)d_in[6];
    const float* Ri     = (const float*)d_in[7];
    const float* bi     = (const float*)d_in[8];
    const float* Wg     = (const float*)d_in[9];
    const float* Rg     = (const float*)d_in[10];
    const float* bg     = (const float*)d_in[11];
    const float* Wc     = (const float*)d_in[12];
    const float* bc     = (const float*)d_in[13];
    const float* init_h = (const float*)d_in[14];
    const float* init_c = (const float*)d_in[15];

    char* w = (char*)d_ws;
    __hip_bfloat16* zbuf = (__hip_bfloat16*)w;  w += (size_t)M_TOT * 512 * 2;
    __hip_bfloat16* fbuf = (__hip_bfloat16*)w;  w += (size_t)M_TOT * NL * 2;
    __hip_bfloat16* ubuf = (__hip_bfloat16*)w;  w += (size_t)M_TOT * NL * 2;
    __hip_bfloat16* WfT  = (__hip_bfloat16*)w;  w += (size_t)NL * IN_DIM * 2;
    __hip_bfloat16* Btig = (__hip_bfloat16*)w;  w += (size_t)1024 * 1024 * 2;
    __hip_bfloat16* Btc  = (__hip_bfloat16*)w;  w += (size_t)NL * NCONN * 2;
    __hip_bfloat16* ihb  = (__hip_bfloat16*)w;  w += 512 * 2;

    // all weight prep + ihb in one launch
    wprep<<<321, 256, 0, stream>>>(Wi, Ri, Wg, Rg, Wf, Wc, init_h,
                                   Btig, WfT, Btc, ihb);

    // z = LN(cos(x^T Wf + bf)) -> zbuf  (x staged in-kernel)
    k1_mfma_fourier_ln<<<M_TOT / 64, 512, 0, stream>>>(
        x, WfT, bfv, gamma, beta, zbuf);

    // fused gates: iu and f paths in one launch (1024 blocks)
    gates_fused<<<1024, 256, 0, stream>>>(zbuf, Btig, conn, Btc, ihb,
                                          bi, bg, bc, fbuf, ubuf);

    k3_scan<<<NB * 8, 64, 0, stream>>>(zbuf, fbuf, ubuf, init_c, (float*)d_out);
}

// Round 15
// 127.316 us; speedup vs baseline: 1.1273x; 1.1273x over previous
//
#include <hip/hip_runtime.h>
#include <hip/hip_bf16.h>

#define NB 32
#define IN_DIM 256
#define NT 512
#define NL 512
#define NCONN 256
#define LN_EPS 1e-3f
#define M_TOT (NB * NT)   // 16384 rows

typedef __attribute__((ext_vector_type(8))) short short8;
typedef __attribute__((ext_vector_type(4))) float f32x4;

__device__ __forceinline__ void async_copy16(void* lds_dst, const void* g_src) {
    __builtin_amdgcn_global_load_lds(
        (const __attribute__((address_space(1))) unsigned int*)g_src,
        (__attribute__((address_space(3))) unsigned int*)lds_dst, 16, 0, 0);
}

__device__ __forceinline__ ushort f2bf(float f) {   // RNE f32->bf16 bits
    unsigned int x = __float_as_uint(f);
    return (ushort)((x + 0x7FFFu + ((x >> 16) & 1u)) >> 16);
}

// ---------------------------------------------------------------------------
// wprep: all weight transposes + ihb fill in ONE launch.
// ---------------------------------------------------------------------------
__global__ __launch_bounds__(256) void wprep(
    const float* __restrict__ Wi, const float* __restrict__ Ri,
    const float* __restrict__ Wg, const float* __restrict__ Rg,
    const float* __restrict__ Wf, const float* __restrict__ Wc,
    const float* __restrict__ init_h,
    __hip_bfloat16* __restrict__ Btig, __hip_bfloat16* __restrict__ WfT,
    __hip_bfloat16* __restrict__ Btc, __hip_bfloat16* __restrict__ ihb)
{
    const int blk = blockIdx.x;
    const int tid = threadIdx.x;
    if (blk == 320) {
        ihb[tid]       = __float2bfloat16(init_h[tid]);
        ihb[tid + 256] = __float2bfloat16(init_h[tid + 256]);
        return;
    }
    const float* src; __hip_bfloat16* dst;
    int N, lddst, k_off, tile;
    if (blk < 64)       { src = Wi; dst = Btig; N = 512; lddst = 1024; k_off = 0;   tile = blk; }
    else if (blk < 128) { src = Ri; dst = Btig; N = 512; lddst = 1024; k_off = 512; tile = blk - 64; }
    else if (blk < 192) { src = Wg; dst = Btig + (size_t)512 * 1024; N = 512; lddst = 1024; k_off = 0;   tile = blk - 128; }
    else if (blk < 256) { src = Rg; dst = Btig + (size_t)512 * 1024; N = 512; lddst = 1024; k_off = 512; tile = blk - 192; }
    else if (blk < 288) { src = Wf; dst = WfT; N = 512; lddst = 256; k_off = 0; tile = blk - 256; }
    else                { src = Wc; dst = Btc; N = 512; lddst = 256; k_off = 0; tile = blk - 288; }

    __shared__ float t[64][65];
    const int ntn = N >> 6;
    const int k0 = (tile / ntn) << 6;
    const int n0 = (tile % ntn) << 6;
    for (int idx = tid; idx < 4096; idx += 256) {
        const int kk = idx >> 6, nn = idx & 63;
        t[kk][nn] = src[(size_t)(k0 + kk) * N + n0 + nn];
    }
    __syncthreads();
    for (int idx = tid; idx < 4096; idx += 256) {
        const int nn = idx >> 6, kk = idx & 63;
        dst[(size_t)(n0 + nn) * lddst + k_off + k0 + kk] = __float2bfloat16(t[kk][nn]);
    }
}

// ---------------------------------------------------------------------------
// Kernel 1 (MFMA 16x16x32): P = x^T @ Wf (64 t-rows x 512 cols per block),
// A staged IN-KERNEL from f32 x[b][k][t], p = cos(P+bf), LN, zbuf bf16.
// ---------------------------------------------------------------------------
__global__ __launch_bounds__(512, 2) void k1_mfma_fourier_ln(
    const float* __restrict__ x,              // [NB][256][512] f32
    const __hip_bfloat16* __restrict__ WfT,   // [512][256]
    const float* __restrict__ bf, const float* __restrict__ gamma,
    const float* __restrict__ beta,
    __hip_bfloat16* __restrict__ zb)
{
    constexpr int ABYTES = 64 * 128;          // 8 KB
    constexpr int BBYTES = 512 * 128;         // 64 KB
    constexpr int NBUFB  = ABYTES + BBYTES;
    __shared__ __align__(16) char lds[2 * NBUFB];     // 144 KB
    __shared__ float pS[64][8], pQ[64][8];
    __shared__ float mS[64], rS[64];

    const int tid  = threadIdx.x;
    const int wave = tid >> 6, lane = tid & 63;
    const int m0 = blockIdx.x * 64;
    const int b  = m0 >> 9;
    const int t0 = m0 & 511;
    const float* xb = x + (size_t)b * IN_DIM * NT;

    f32x4 acc[4][4];
#pragma unroll
    for (int mi = 0; mi < 4; mi++)
#pragma unroll
        for (int ni = 0; ni < 4; ni++) acc[mi][ni] = f32x4{0.f, 0.f, 0.f, 0.f};

    const int rowq = tid >> 3;
    const int sswz = ((tid & 7) ^ (rowq & 7)) << 4;
    const char* Bb = (const char*)WfT;

    auto stage = [&](int buf, int kt) {
        char* base = lds + buf * NBUFB;
#pragma unroll
        for (int j = 0; j < 2; j++) {
            const int ci = j * 512 + tid;
            const int k  = ci >> 4;
            const int tc = ci & 15;
            const float4 v = *(const float4*)(
                xb + ((size_t)(kt * 64 + k)) * NT + t0 + tc * 4);
            const ushort h[4] = {f2bf(v.x), f2bf(v.y), f2bf(v.z), f2bf(v.w)};
            const int sl = k >> 3, kb2 = (k & 7) << 1;
#pragma unroll
            for (int e = 0; e < 4; e++) {
                const int t = tc * 4 + e;
                *(ushort*)(base + t * 128 + (((sl) ^ (t & 7)) << 4) + kb2) = h[e];
            }
        }
        const size_t kb = (size_t)kt * 128;
#pragma unroll
        for (int j = 0; j < 8; j++) {
            const int row = j * 64 + rowq;
            async_copy16(base + ABYTES + (j * 512 + tid) * 16,
                         Bb + (size_t)row * 512 + kb + sswz);
        }
    };

    const int l15 = lane & 15, lq = lane >> 4, l7 = lane & 7;
    int kxB[2];
#pragma unroll
    for (int ks = 0; ks < 2; ks++) kxB[ks] = ((ks * 4 + lq) ^ l7) << 4;

    stage(0, 0);
    int cur = 0;
#pragma unroll 1
    for (int kt = 0; kt < 4; kt++) {
        __syncthreads();
        if (kt + 1 < 4) stage(cur ^ 1, kt + 1);
        const char* sA = lds + cur * NBUFB;
        const char* sB = sA + ABYTES;
#pragma unroll
        for (int ks = 0; ks < 2; ks++) {
            const int kx = kxB[ks];
            short8 a[4], b[4];
#pragma unroll
            for (int mi = 0; mi < 4; mi++)
                a[mi] = *(const short8*)(sA + (size_t)(mi * 16 + l15) * 128 + kx);
#pragma unroll
            for (int ni = 0; ni < 4; ni++)
                b[ni] = *(const short8*)(sB +
                    (size_t)(wave * 64 + ni * 16 + l15) * 128 + kx);
#pragma unroll
            for (int ni = 0; ni < 4; ni++)
#pragma unroll
                for (int mi = 0; mi < 4; mi++)
                    acc[mi][ni] = __builtin_amdgcn_mfma_f32_16x16x32_bf16(
                        a[mi], b[ni], acc[mi][ni], 0, 0, 0);
        }
        cur ^= 1;
    }

    int cg[4]; float bfc[4];
#pragma unroll
    for (int ni = 0; ni < 4; ni++) {
        cg[ni] = wave * 64 + ni * 16 + l15;
        bfc[ni] = bf[cg[ni]];
    }

#pragma unroll
    for (int mi = 0; mi < 4; mi++) {
#pragma unroll
        for (int r = 0; r < 4; r++) {
            float s = 0.f, q = 0.f;
#pragma unroll
            for (int ni = 0; ni < 4; ni++) {
                const float p = __cosf(acc[mi][ni][r] + bfc[ni]);
                s += p; q += p * p;
            }
#pragma unroll
            for (int off = 8; off >= 1; off >>= 1) {
                s += __shfl_xor(s, off);
                q += __shfl_xor(q, off);
            }
            if (l15 == 0) {
                const int row = mi * 16 + lq * 4 + r;
                pS[row][wave] = s;
                pQ[row][wave] = q;
            }
        }
    }
    __syncthreads();
    if (tid < 64) {
        float a = 0.f, qq = 0.f;
#pragma unroll
        for (int w = 0; w < 8; w++) { a += pS[tid][w]; qq += pQ[tid][w]; }
        const float mu = a * (1.0f / NL);
        const float var = qq * (1.0f / NL) - mu * mu;
        mS[tid] = mu;
        rS[tid] = rsqrtf(var + LN_EPS);
    }
    __syncthreads();

    float gm[4], bt[4];
#pragma unroll
    for (int ni = 0; ni < 4; ni++) { gm[ni] = gamma[cg[ni]]; bt[ni] = beta[cg[ni]]; }

#pragma unroll
    for (int mi = 0; mi < 4; mi++) {
#pragma unroll
        for (int r = 0; r < 4; r++) {
            const int row = mi * 16 + lq * 4 + r;
            const int m = m0 + row;
            const float mu = mS[row], rs = rS[row];
#pragma unroll
            for (int ni = 0; ni < 4; ni++) {
                const float p = __cosf(acc[mi][ni][r] + bfc[ni]);
                const float z = gm[ni] * (p - mu) * rs + bt[ni];
                zb[(size_t)m * 512 + cg[ni]] = __float2bfloat16(z);
            }
        }
    }
}

// ---------------------------------------------------------------------------
// Shared pieces for the gates kernels (128x128 tile, 4 waves, single 32 KB buf)
// ---------------------------------------------------------------------------
#define GATES_PRELUDE                                                         \
    const int tid  = threadIdx.x;                                             \
    const int wave = tid >> 6, lane = tid & 63;                               \
    const int wm = wave >> 1, wn = wave & 1;                                  \
    const int d = blockIdx.x;                                                 \
    const int L = (d & 7) * 64 + (d >> 3);                                    \
    const int m0 = (L >> 2) << 7;                                             \
    const int n0 = (L & 3) << 7;                                              \
    const int l15 = lane & 15, lq = lane >> 4, l7 = lane & 7;                 \
    int kx[2];                                                                \
    kx[0] = (lq ^ l7) << 4;                                                   \
    kx[1] = ((4 + lq) ^ l7) << 4;

#define STAGE_AZ(kt)                                                          \
    {                                                                         \
        _Pragma("unroll")                                                     \
        for (int j = 0; j < 4; j++) {                                         \
            const int i = j * 256 + tid;                                      \
            const int r = i >> 3;                                             \
            const int sl = (i & 7) ^ (r & 7);                                 \
            const int ke = (kt) * 64 + sl * 8;                                \
            const __hip_bfloat16* srcA;                                       \
            const int m = m0 + r;                                             \
            if (ke < 512) {                                                   \
                srcA = Az + (size_t)m * 512 + ke;                             \
            } else {                                                          \
                const int k2 = ke - 512;                                      \
                srcA = ((m & (NT - 1)) == 0) ? (ihb + k2)                     \
                                             : (Az + (size_t)(m - 1) * 512 + k2); \
            }                                                                 \
            async_copy16(lds + i * 16, srcA);                                 \
            async_copy16(lds + 16384 + i * 16,                                \
                         Bg + (size_t)(n0 + r) * 1024 + ke);                  \
        }                                                                     \
    }

#define COMPUTE_TILE(ACC)                                                     \
    {                                                                         \
        const char* sA = lds;                                                 \
        const char* sB = lds + 16384;                                         \
        _Pragma("unroll")                                                     \
        for (int ks = 0; ks < 2; ks++) {                                      \
            short8 a[4], b[4];                                                \
            _Pragma("unroll")                                                 \
            for (int mi = 0; mi < 4; mi++)                                    \
                a[mi] = *(const short8*)(sA +                                 \
                    (size_t)(wm * 64 + mi * 16 + l15) * 128 + kx[ks]);        \
            _Pragma("unroll")                                                 \
            for (int ni = 0; ni < 4; ni++)                                    \
                b[ni] = *(const short8*)(sB +                                 \
                    (size_t)(wn * 64 + ni * 16 + l15) * 128 + kx[ks]);        \
            _Pragma("unroll")                                                 \
            for (int ni = 0; ni < 4; ni++)                                    \
                _Pragma("unroll")                                             \
                for (int mi = 0; mi < 4; mi++)                                \
                    ACC[mi][ni] = __builtin_amdgcn_mfma_f32_16x16x32_bf16(    \
                        a[mi], b[ni], ACC[mi][ni], 0, 0, 0);                  \
        }                                                                     \
    }

// ---------------------------------------------------------------------------
// gates_f: f = sigmoid([z|z_prev] @ [Wg;Rg]^T + bg) -> fbuf.  (Bg pre-offset)
// ---------------------------------------------------------------------------
__global__ __launch_bounds__(256, 4) void gates_f(
    const __hip_bfloat16* __restrict__ Az,
    const __hip_bfloat16* __restrict__ Bg,    // Btig + 512*1024
    const __hip_bfloat16* __restrict__ ihb,
    const float* __restrict__ bg,
    __hip_bfloat16* __restrict__ fb)
{
    __shared__ __align__(16) char lds[32768];
    GATES_PRELUDE

    f32x4 acc[4][4];
#pragma unroll
    for (int mi = 0; mi < 4; mi++)
#pragma unroll
        for (int ni = 0; ni < 4; ni++) acc[mi][ni] = f32x4{0.f, 0.f, 0.f, 0.f};

#pragma unroll 1
    for (int kt = 0; kt < 16; kt++) {
        STAGE_AZ(kt)
        __syncthreads();
        COMPUTE_TILE(acc)
        __syncthreads();
    }

#pragma unroll
    for (int ni = 0; ni < 4; ni++) {
        const int gcol = n0 + wn * 64 + ni * 16 + l15;
        const float bgl = bg[gcol];
#pragma unroll
        for (int mi = 0; mi < 4; mi++)
#pragma unroll
            for (int r = 0; r < 4; r++) {
                const int m = m0 + wm * 64 + mi * 16 + lq * 4 + r;
                const float fv = 1.f / (1.f + __expf(-(acc[mi][ni][r] + bgl)));
                fb[(size_t)m * 512 + gcol] = __float2bfloat16(fv);
            }
    }
}

// ---------------------------------------------------------------------------
// gates_iu: u-phase (conn f32 reg-staged @ Wc^T, K=256) then main GEMM
// ([z|z_prev] @ [Wi;Ri]^T, K=1024); iu = sigmoid(acc+bi)*(acc_u+bc) -> ubuf.
// launch_bounds (256,3): VGPR=100 fits 3 blocks/CU (was 2 in R12 -> Occ fix).
// ---------------------------------------------------------------------------
__global__ __launch_bounds__(256, 3) void gates_iu(
    const __hip_bfloat16* __restrict__ Az,
    const __hip_bfloat16* __restrict__ Bg,    // Btig (rows [Wi;Ri]^T)
    const float* __restrict__ conn,           // [M][256] f32
    const __hip_bfloat16* __restrict__ Btc,   // [512][256] Wc^T
    const __hip_bfloat16* __restrict__ ihb,
    const float* __restrict__ bi, const float* __restrict__ bc,
    __hip_bfloat16* __restrict__ ub)
{
    __shared__ __align__(16) char lds[32768];
    GATES_PRELUDE

    f32x4 accu[4][4];
#pragma unroll
    for (int mi = 0; mi < 4; mi++)
#pragma unroll
        for (int ni = 0; ni < 4; ni++) accu[mi][ni] = f32x4{0.f, 0.f, 0.f, 0.f};

    // ---- u phase: 4 K-steps over conn (f32 reg-staged) x Btc ----
#pragma unroll 1
    for (int kt = 0; kt < 4; kt++) {
#pragma unroll
        for (int j = 0; j < 8; j++) {
            const int ci = j * 256 + tid;     // 0..2047
            const int r  = ci >> 4;           // 0..127
            const int c4 = ci & 15;           // which float4 in row
            const float4 v = *(const float4*)(
                conn + (size_t)(m0 + r) * NCONN + kt * 64 + c4 * 4);
            ushort4 h;
            h.x = f2bf(v.x); h.y = f2bf(v.y); h.z = f2bf(v.z); h.w = f2bf(v.w);
            const int sl = c4 >> 1, half = c4 & 1;
            *(ushort4*)(lds + r * 128 + ((sl ^ (r & 7)) << 4) + half * 8) = h;
        }
#pragma unroll
        for (int j = 0; j < 4; j++) {
            const int i = j * 256 + tid;
            const int r = i >> 3;
            const int sl = (i & 7) ^ (r & 7);
            const int ke = kt * 64 + sl * 8;
            async_copy16(lds + 16384 + i * 16,
                         Btc + (size_t)(n0 + r) * NCONN + ke);
        }
        __syncthreads();
        COMPUTE_TILE(accu)
        __syncthreads();
    }

    // ---- main phase: 16 K-steps over [z|z_prev] x [Wi;Ri]^T ----
    f32x4 acc[4][4];
#pragma unroll
    for (int mi = 0; mi < 4; mi++)
#pragma unroll
        for (int ni = 0; ni < 4; ni++) acc[mi][ni] = f32x4{0.f, 0.f, 0.f, 0.f};

#pragma unroll 1
    for (int kt = 0; kt < 16; kt++) {
        STAGE_AZ(kt)
        __syncthreads();
        COMPUTE_TILE(acc)
        __syncthreads();
    }

#pragma unroll
    for (int ni = 0; ni < 4; ni++) {
        const int gcol = n0 + wn * 64 + ni * 16 + l15;
        const float bil = bi[gcol], bcl = bc[gcol];
#pragma unroll
        for (int mi = 0; mi < 4; mi++)
#pragma unroll
            for (int r = 0; r < 4; r++) {
                const int m = m0 + wm * 64 + mi * 16 + lq * 4 + r;
                const float iv = 1.f / (1.f + __expf(-(acc[mi][ni][r] + bil)));
                const float uv = accu[mi][ni][r] + bcl;
                ub[(size_t)m * 512 + gcol] = __float2bfloat16(iv * uv);
            }
    }
}

// ---------------------------------------------------------------------------
// Kernel 3: sequential scan; h = sin(z)*c; out[b,l,t].
// ---------------------------------------------------------------------------
__global__ __launch_bounds__(64) void k3_scan(
    const __hip_bfloat16* __restrict__ zb,
    const __hip_bfloat16* __restrict__ fb,
    const __hip_bfloat16* __restrict__ ub,
    const float* __restrict__ init_c, float* __restrict__ out)
{
    const int b = blockIdx.x >> 3;
    const int l = ((blockIdx.x & 7) << 6) + threadIdx.x;
    float c = init_c[l];

    const __hip_bfloat16* zp = zb + (size_t)b * NT * 512 + l;
    const __hip_bfloat16* fp = fb + (size_t)b * NT * NL + l;
    const __hip_bfloat16* ip = ub + (size_t)b * NT * NL + l;
    float* op = out + ((size_t)b * NL + l) * NT;

    for (int t0 = 0; t0 < NT; t0 += 16) {
        float fv[16], iv[16], zv[16];
#pragma unroll
        for (int j = 0; j < 16; j++) {
            fv[j] = __bfloat162float(fp[(size_t)(t0 + j) * NL]);
            iv[j] = __bfloat162float(ip[(size_t)(t0 + j) * NL]);
            zv[j] = __bfloat162float(zp[(size_t)(t0 + j) * 512]);
        }
        float h[16];
#pragma unroll
        for (int j = 0; j < 16; j++) {
            c = fv[j] * c + iv[j];
            h[j] = __sinf(zv[j]) * c;
        }
        float4* o4 = (float4*)(op + t0);
        o4[0] = make_float4(h[0],  h[1],  h[2],  h[3]);
        o4[1] = make_float4(h[4],  h[5],  h[6],  h[7]);
        o4[2] = make_float4(h[8],  h[9],  h[10], h[11]);
        o4[3] = make_float4(h[12], h[13], h[14], h[15]);
    }
}

// ---------------------------------------------------------------------------
extern "C" void kernel_launch(void* const* d_in, const int* in_sizes, int n_in,
                              void* d_out, int out_size, void* d_ws, size_t ws_size,
                              hipStream_t stream)
{
    const float* x      = (const float*)d_in[0];
    const float* conn   = (const float*)d_in[1];
    const float* Wf     = (const float*)d_in[2];
    const float* bfv    = (const float*)d_in[3];
    const float* gamma  = (const float*)d_in[4];
    const float* beta   = (const float*)d_in[5];
    const float* Wi     = (const float*)d_in[6];
    const float* Ri     = (const float*)d_in[7];
    const float* bi     = (const float*)d_in[8];
    const float* Wg     = (const float*)d_in[9];
    const float* Rg     = (const float*)d_in[10];
    const float* bg     = (const float*)d_in[11];
    const float* Wc     = (const float*)d_in[12];
    const float* bc     = (const float*)d_in[13];
    const float* init_h = (const float*)d_in[14];
    const float* init_c = (const float*)d_in[15];

    char* w = (char*)d_ws;
    __hip_bfloat16* zbuf = (__hip_bfloat16*)w;  w += (size_t)M_TOT * 512 * 2;
    __hip_bfloat16* fbuf = (__hip_bfloat16*)w;  w += (size_t)M_TOT * NL * 2;
    __hip_bfloat16* ubuf = (__hip_bfloat16*)w;  w += (size_t)M_TOT * NL * 2;
    __hip_bfloat16* WfT  = (__hip_bfloat16*)w;  w += (size_t)NL * IN_DIM * 2;
    __hip_bfloat16* Btig = (__hip_bfloat16*)w;  w += (size_t)1024 * 1024 * 2;
    __hip_bfloat16* Btc  = (__hip_bfloat16*)w;  w += (size_t)NL * NCONN * 2;
    __hip_bfloat16* ihb  = (__hip_bfloat16*)w;  w += 512 * 2;

    // all weight prep + ihb in one launch
    wprep<<<321, 256, 0, stream>>>(Wi, Ri, Wg, Rg, Wf, Wc, init_h,
                                   Btig, WfT, Btc, ihb);

    // z = LN(cos(x^T Wf + bf)) -> zbuf  (x staged in-kernel)
    k1_mfma_fourier_ln<<<M_TOT / 64, 512, 0, stream>>>(
        x, WfT, bfv, gamma, beta, zbuf);

    // iu = sigmoid([z|zp]@[Wi;Ri]^T + bi) * (conn@Wc + bc)   (512 blocks)
    gates_iu<<<512, 256, 0, stream>>>(zbuf, Btig, conn, Btc, ihb, bi, bc, ubuf);

    // f = sigmoid([z|zp]@[Wg;Rg]^T + bg)                     (512 blocks)
    gates_f<<<512, 256, 0, stream>>>(zbuf, Btig + (size_t)512 * 1024, ihb, bg, fbuf);

    k3_scan<<<NB * 8, 64, 0, stream>>>(zbuf, fbuf, ubuf, init_c, (float*)d_out);
}